// Round 1
// baseline (1169.512 us; speedup 1.0000x reference)
//
#include <hip/hip_runtime.h>
#include <math.h>

#define B_   16
#define T_   256
#define V_   25
#define D_   128
#define H_   8
#define DH   16
#define BV_  (B_*V_)        // 400
#define MAXT 300
#define NREL (2*MAXT-1)     // 599
#define TT   8              // tokens per workgroup in GEMM kernels

// -------- block-wide (128 threads = 2 waves) sum reduction --------
__device__ inline float blockReduceSum128(float val, float* red, int tid) {
  #pragma unroll
  for (int off = 32; off > 0; off >>= 1) val += __shfl_down(val, off, 64);
  __syncthreads();                       // protect red reuse across calls
  if ((tid & 63) == 0) red[tid >> 6] = val;
  __syncthreads();
  return red[0] + red[1];
}

// ---------------- K1: LN1 + QKV GEMM + q/k normalization ----------------
// grid: BV*(T/TT) blocks, 128 threads. Outputs q,k,v in [BV,H,T,16] layout.
__global__ __launch_bounds__(128) void k1_ln_qkv(
    const float* __restrict__ x, const float* __restrict__ g1, const float* __restrict__ b1,
    const float* __restrict__ qkv_w, const float* __restrict__ qkv_b,
    const float* __restrict__ logit_scale,
    float* __restrict__ qb, float* __restrict__ kb, float* __restrict__ vb)
{
  __shared__ float xn[TT][D_];
  __shared__ float qs[TT][D_];
  __shared__ float ks[TT][D_];
  __shared__ float red[2];
  const int tid = threadIdx.x;
  const int blk = blockIdx.x;
  const int bv  = blk / (T_/TT);
  const int t0  = (blk % (T_/TT)) * TT;
  const int b   = bv / V_, v = bv % V_;

  const float gg = g1[tid], bb = b1[tid];
  for (int tt = 0; tt < TT; ++tt) {
    float val = x[(((size_t)b*T_ + (t0+tt))*V_ + v)*D_ + tid];
    float s   = blockReduceSum128(val, red, tid);
    float mean = s * (1.0f/128.0f);
    float d    = val - mean;
    float s2   = blockReduceSum128(d*d, red, tid);
    xn[tt][tid] = d * rsqrtf(s2*(1.0f/128.0f) + 1e-5f) * gg + bb;
  }
  __syncthreads();

  float accq[TT], acck[TT], accv[TT];
  {
    const float bq = qkv_b[tid], bk = qkv_b[128+tid], bvv = qkv_b[256+tid];
    #pragma unroll
    for (int tt = 0; tt < TT; ++tt) { accq[tt]=bq; acck[tt]=bk; accv[tt]=bvv; }
  }
  for (int i = 0; i < D_; ++i) {
    float wq = qkv_w[i*384 + tid];
    float wk = qkv_w[i*384 + 128 + tid];
    float wv = qkv_w[i*384 + 256 + tid];
    #pragma unroll
    for (int tt = 0; tt < TT; ++tt) {
      float xi = xn[tt][i];
      accq[tt] += xi*wq; acck[tt] += xi*wk; accv[tt] += xi*wv;
    }
  }
  #pragma unroll
  for (int tt = 0; tt < TT; ++tt) { qs[tt][tid]=accq[tt]; ks[tt][tid]=acck[tt]; }
  __syncthreads();

  const int h = tid >> 4, dd = tid & 15;
  const float scale = expf(fminf(logit_scale[h], 4.605170185988091f)); // log(100)
  const size_t obase = ((size_t)bv*H_ + h)*T_*DH + dd;
  for (int tt = 0; tt < TT; ++tt) {
    float sq = 0.f, sk = 0.f;
    const int base = h*16;
    #pragma unroll
    for (int j = 0; j < 16; ++j) {
      float a = qs[tt][base+j]; sq += a*a;
      float c = ks[tt][base+j]; sk += c*c;
    }
    float qn = accq[tt] / fmaxf(sqrtf(sq), 1e-12f) * scale;
    float kn = acck[tt] / fmaxf(sqrtf(sk), 1e-12f);
    size_t o = obase + (size_t)(t0+tt)*DH;
    qb[o] = qn; kb[o] = kn; vb[o] = accv[tt];
  }
}

// ---------------- K2: attention (scores + softmax + PV), in-place over q ----
// grid: BV*H blocks, 256 threads (one query row per thread).
__global__ __launch_bounds__(256) void k2_attn(
    const float* __restrict__ rel_pos_bias,
    float* __restrict__ qb, const float* __restrict__ kb, const float* __restrict__ vb)
{
  __shared__ float kn_s[T_][DH];
  __shared__ float v_s [T_][DH];
  __shared__ float bias_s[NREL];
  const int tid = threadIdx.x;
  const int bh  = blockIdx.x;          // bv*H + h
  const int h   = bh & (H_-1);
  const size_t base = (size_t)bh * T_ * DH;

  for (int j = tid; j < T_*DH; j += 256) {
    ((float*)kn_s)[j] = kb[base + j];
    ((float*)v_s )[j] = vb[base + j];
  }
  for (int j = tid; j < NREL; j += 256) bias_s[j] = rel_pos_bias[h*NREL + j];

  float qr[DH];
  #pragma unroll
  for (int dd = 0; dd < DH; ++dd) qr[dd] = qb[base + (size_t)tid*DH + dd];
  __syncthreads();   // all q reads done before any thread can reach the store

  float l = 0.f, o[DH];
  #pragma unroll
  for (int dd = 0; dd < DH; ++dd) o[dd] = 0.f;
  const float* bptr = bias_s + (MAXT-1) + tid;  // bptr[-s] = bias[h, tid-s+299]
  // scores are bounded: |qn.kn|/4 <= scale/4 <= 25, so no max-subtraction needed
  for (int s = 0; s < T_; ++s) {
    float dot = 0.f;
    #pragma unroll
    for (int dd = 0; dd < DH; ++dd) dot += qr[dd]*kn_s[s][dd];
    float p = __expf(dot * 0.25f + bptr[-s]);
    l += p;
    #pragma unroll
    for (int dd = 0; dd < DH; ++dd) o[dd] += p * v_s[s][dd];
  }
  const float inv = 1.0f / l;
  #pragma unroll
  for (int dd = 0; dd < DH; ++dd) qb[base + (size_t)tid*DH + dd] = o[dd]*inv;
}

// ---------------- K3: out@proj_w + proj_b + residual -> xf2 ----------------
__global__ __launch_bounds__(128) void k3_proj(
    const float* __restrict__ x, const float* __restrict__ att,
    const float* __restrict__ proj_w, const float* __restrict__ proj_b,
    float* __restrict__ xf2)
{
  __shared__ float a_s[TT][D_];
  const int tid = threadIdx.x, blk = blockIdx.x;
  const int bv = blk / (T_/TT), t0 = (blk % (T_/TT)) * TT;
  const int b = bv / V_, v = bv % V_;
  const int h = tid >> 4, dd = tid & 15;
  for (int tt = 0; tt < TT; ++tt)
    a_s[tt][tid] = att[(((size_t)bv*H_ + h)*T_ + (t0+tt))*DH + dd];
  __syncthreads();

  float acc[TT];
  #pragma unroll
  for (int tt = 0; tt < TT; ++tt) acc[tt] = 0.f;
  for (int i = 0; i < D_; ++i) {
    float w = proj_w[i*D_ + tid];
    #pragma unroll
    for (int tt = 0; tt < TT; ++tt) acc[tt] += a_s[tt][i]*w;
  }
  const float pb = proj_b[tid];
  for (int tt = 0; tt < TT; ++tt) {
    float res = x[(((size_t)b*T_ + (t0+tt))*V_ + v)*D_ + tid];
    xf2[((size_t)bv*T_ + (t0+tt))*D_ + tid] = res + acc[tt] + pb;
  }
}

// ---------------- K4: LN2 + FFN (gelu) + residual -> d_out (permuted) -------
__global__ __launch_bounds__(128) void k4_ffn(
    const float* __restrict__ xf2, const float* __restrict__ g2, const float* __restrict__ b2,
    const float* __restrict__ w1, const float* __restrict__ fb1,
    const float* __restrict__ w2, const float* __restrict__ fb2,
    float* __restrict__ out)
{
  __shared__ float y_s[TT][D_];
  __shared__ float h_s[TT][512];
  __shared__ float red[2];
  const int tid = threadIdx.x, blk = blockIdx.x;
  const int bv = blk / (T_/TT), t0 = (blk % (T_/TT)) * TT;
  const int b = bv / V_, v = bv % V_;

  const float gg = g2[tid], bbv = b2[tid];
  float xf[TT];
  for (int tt = 0; tt < TT; ++tt) {
    float val = xf2[((size_t)bv*T_ + t0+tt)*D_ + tid];
    xf[tt] = val;
    float s  = blockReduceSum128(val, red, tid);
    float mean = s * (1.0f/128.0f);
    float d  = val - mean;
    float s2 = blockReduceSum128(d*d, red, tid);
    y_s[tt][tid] = d * rsqrtf(s2*(1.0f/128.0f) + 1e-5f) * gg + bbv;
  }
  __syncthreads();

  float acc[4][TT];
  #pragma unroll
  for (int c = 0; c < 4; ++c) {
    float bc = fb1[c*128 + tid];
    #pragma unroll
    for (int tt = 0; tt < TT; ++tt) acc[c][tt] = bc;
  }
  for (int i = 0; i < D_; ++i) {
    float w0 = w1[i*512 +       tid];
    float wA = w1[i*512 + 128 + tid];
    float wB = w1[i*512 + 256 + tid];
    float wC = w1[i*512 + 384 + tid];
    #pragma unroll
    for (int tt = 0; tt < TT; ++tt) {
      float yi = y_s[tt][i];
      acc[0][tt] += yi*w0; acc[1][tt] += yi*wA;
      acc[2][tt] += yi*wB; acc[3][tt] += yi*wC;
    }
  }
  #pragma unroll
  for (int c = 0; c < 4; ++c)
    #pragma unroll
    for (int tt = 0; tt < TT; ++tt) {
      float u = acc[c][tt];
      h_s[tt][c*128 + tid] = 0.5f*u*(1.0f + erff(u*0.70710678118654752f));
    }
  __syncthreads();

  float acc2[TT];
  const float bo = fb2[tid];
  #pragma unroll
  for (int tt = 0; tt < TT; ++tt) acc2[tt] = bo;
  for (int j = 0; j < 512; ++j) {
    float w = w2[j*128 + tid];
    #pragma unroll
    for (int tt = 0; tt < TT; ++tt) acc2[tt] += h_s[tt][j]*w;
  }
  for (int tt = 0; tt < TT; ++tt)
    out[(((size_t)b*T_ + t0+tt)*V_ + v)*D_ + tid] = xf[tt] + acc2[tt];
}

extern "C" void kernel_launch(void* const* d_in, const int* in_sizes, int n_in,
                              void* d_out, int out_size, void* d_ws, size_t ws_size,
                              hipStream_t stream)
{
  (void)in_sizes; (void)n_in; (void)out_size; (void)ws_size;
  const float* x     = (const float*)d_in[0];
  const float* g1    = (const float*)d_in[1];
  const float* b1    = (const float*)d_in[2];
  const float* qkv_w = (const float*)d_in[3];
  const float* qkv_b = (const float*)d_in[4];
  const float* pw    = (const float*)d_in[5];
  const float* pb    = (const float*)d_in[6];
  const float* ls    = (const float*)d_in[7];
  const float* rpb   = (const float*)d_in[8];
  const float* g2    = (const float*)d_in[9];
  const float* b2    = (const float*)d_in[10];
  const float* w1    = (const float*)d_in[11];
  const float* fb1   = (const float*)d_in[12];
  const float* w2    = (const float*)d_in[13];
  const float* fb2   = (const float*)d_in[14];
  float* out = (float*)d_out;

  const size_t n = (size_t)BV_*T_*D_;      // 13,107,200 elements
  float* qb  = (float*)d_ws;               // q -> overwritten in-place with attn out
  float* kb  = qb + n;
  float* xf2 = kb + n;
  float* vb  = out;                        // alias v onto d_out (fully rewritten by k4)

  k1_ln_qkv<<<BV_*(T_/TT), dim3(128), 0, stream>>>(x, g1, b1, qkv_w, qkv_b, ls, qb, kb, vb);
  k2_attn  <<<BV_*H_,      dim3(256), 0, stream>>>(rpb, qb, kb, vb);
  k3_proj  <<<BV_*(T_/TT), dim3(128), 0, stream>>>(x, qb, pw, pb, xf2);
  k4_ffn   <<<BV_*(T_/TT), dim3(128), 0, stream>>>(xf2, g2, b2, w1, fb1, w2, fb2, out);
}

// Round 2
// 652.247 us; speedup vs baseline: 1.7931x; 1.7931x over previous
//
#include <hip/hip_runtime.h>
#include <hip/hip_fp16.h>
#include <math.h>

#define B_   16
#define T_   256
#define V_   25
#define D_   128
#define H_   8
#define DH   16
#define BV_  (B_*V_)        // 400
#define MAXT 300
#define NREL (2*MAXT-1)     // 599

typedef __attribute__((ext_vector_type(8))) short short8;
typedef __attribute__((ext_vector_type(4))) float f32x4;

__device__ inline short f2bf(float f) {
  union { float f; unsigned u; } a; a.f = f;
  unsigned r = (a.u + 0x7FFF + ((a.u >> 16) & 1)) >> 16;   // RNE
  return (short)r;
}

// ---------------- K0: weight prep (fp32 -> bf16, transposed to [N][K]) ------
__global__ __launch_bounds__(256) void k0_prep(
    const float* __restrict__ qkv_w, const float* __restrict__ pw,
    const float* __restrict__ w1,    const float* __restrict__ w2,
    short* __restrict__ qkv_wt, short* __restrict__ pwt,
    short* __restrict__ w1t,    short* __restrict__ w2t)
{
  int i = blockIdx.x*256 + threadIdx.x;
  if (i < 384*128) { int n = i >> 7, k = i & 127; qkv_wt[i] = f2bf(qkv_w[k*384 + n]); }
  if (i < 128*128) { int n = i >> 7, k = i & 127; pwt[i]    = f2bf(pw[k*128 + n]); }
  if (i < 512*128) { int n = i >> 7, k = i & 127; w1t[i]    = f2bf(w1[k*512 + n]); }
  if (i < 128*512) { int n = i >> 9, k = i & 511; w2t[i]    = f2bf(w2[k*128 + n]); }
}

// ---------------- K1: LN1 + QKV (MFMA) + q/k head-norm ----------------------
// grid: BV*(T/16), 256 thr (4 waves). Out: qb,kb fp16 [BV][H][T][16], vb fp32.
__global__ __launch_bounds__(256) void k1_ln_qkv(
    const float* __restrict__ x, const float* __restrict__ g1, const float* __restrict__ b1,
    const short* __restrict__ qkv_wt, const float* __restrict__ qkv_b,
    const float* __restrict__ logit_scale,
    __half* __restrict__ qb, __half* __restrict__ kb, float* __restrict__ vb)
{
  __shared__ short xn[16][136];
  const int tid = threadIdx.x;
  const int bv  = blockIdx.x / (T_/16);
  const int t0  = (blockIdx.x % (T_/16)) * 16;
  const int b   = bv / V_, v = bv % V_;

  { // LN: 16 threads per token, 8 elems each
    const int tok = tid >> 4, j = tid & 15;
    const float* xp = x + (((size_t)b*T_ + (t0+tok))*V_ + v)*D_ + j*8;
    float4 a0 = *(const float4*)xp;
    float4 a1 = *(const float4*)(xp+4);
    float e[8] = {a0.x,a0.y,a0.z,a0.w,a1.x,a1.y,a1.z,a1.w};
    float s = 0.f;
    #pragma unroll
    for (int q = 0; q < 8; ++q) s += e[q];
    #pragma unroll
    for (int m = 1; m < 16; m <<= 1) s += __shfl_xor(s, m, 16);
    float mean = s * (1.0f/128.0f);
    float s2 = 0.f;
    #pragma unroll
    for (int q = 0; q < 8; ++q) { float d = e[q]-mean; s2 += d*d; }
    #pragma unroll
    for (int m = 1; m < 16; m <<= 1) s2 += __shfl_xor(s2, m, 16);
    float rstd = rsqrtf(s2*(1.0f/128.0f) + 1e-5f);
    float4 gA = *(const float4*)(g1 + j*8), gB = *(const float4*)(g1 + j*8 + 4);
    float4 bA = *(const float4*)(b1 + j*8), bB = *(const float4*)(b1 + j*8 + 4);
    float gg[8] = {gA.x,gA.y,gA.z,gA.w,gB.x,gB.y,gB.z,gB.w};
    float bb[8] = {bA.x,bA.y,bA.z,bA.w,bB.x,bB.y,bB.z,bB.w};
    short8 o;
    #pragma unroll
    for (int q = 0; q < 8; ++q) o[q] = f2bf((e[q]-mean)*rstd*gg[q] + bb[q]);
    *(short8*)&xn[tok][j*8] = o;
  }
  __syncthreads();

  const int wave = tid >> 6, lane = tid & 63;
  const int col = lane & 15, quad = lane >> 4;
  short8 af[4];
  #pragma unroll
  for (int kk = 0; kk < 4; ++kk) af[kk] = *(const short8*)&xn[col][kk*32 + quad*8];

  for (int it = 0; it < 6; ++it) {
    const int tile = wave*6 + it;           // 0..23: 0-7 q, 8-15 k, 16-23 v
    const int n0 = tile*16;
    f32x4 acc = {0.f,0.f,0.f,0.f};
    #pragma unroll
    for (int kk = 0; kk < 4; ++kk) {
      short8 bf = *(const short8*)(qkv_wt + (size_t)(n0+col)*128 + kk*32 + quad*8);
      acc = __builtin_amdgcn_mfma_f32_16x16x32_bf16(af[kk], bf, acc, 0, 0, 0);
    }
    const float bias = qkv_b[n0+col];
    float val[4];
    #pragma unroll
    for (int r = 0; r < 4; ++r) val[r] = acc[r] + bias;
    const int h = tile & 7;
    const size_t obase = ((size_t)(bv*H_ + h)*T_ + (t0 + quad*4))*DH + col;
    if (tile < 16) {
      float inv[4];
      #pragma unroll
      for (int r = 0; r < 4; ++r) {
        float s = val[r]*val[r];
        #pragma unroll
        for (int m = 1; m < 16; m <<= 1) s += __shfl_xor(s, m, 16);
        inv[r] = 1.0f / fmaxf(sqrtf(s), 1e-12f);
      }
      if (tile < 8) {
        const float scale = __expf(fminf(logit_scale[h], 4.605170185988091f));
        #pragma unroll
        for (int r = 0; r < 4; ++r) qb[obase + (size_t)r*DH] = __float2half(val[r]*inv[r]*scale);
      } else {
        #pragma unroll
        for (int r = 0; r < 4; ++r) kb[obase + (size_t)r*DH] = __float2half(val[r]*inv[r]);
      }
    } else {
      #pragma unroll
      for (int r = 0; r < 4; ++r) vb[obase + (size_t)r*DH] = val[r];
    }
  }
}

// ---------------- K2: attention, out token-major into xf2 -------------------
// grid: BV*H blocks, 256 threads (one query row per thread).
__global__ __launch_bounds__(256) void k2_attn(
    const float* __restrict__ rel_pos_bias,
    const __half* __restrict__ qb, const __half* __restrict__ kb,
    const float* __restrict__ vb, float* __restrict__ xattn)
{
  __shared__ float kn_s[T_][DH];
  __shared__ float v_s [T_][DH];
  __shared__ float bias_s[NREL];
  const int tid = threadIdx.x;
  const int bh  = blockIdx.x;          // bv*H + h
  const int h   = bh & (H_-1);
  const int bv  = bh >> 3;
  const size_t base = (size_t)bh * T_ * DH;

  for (int j = tid; j < T_*DH; j += 256) {
    ((float*)kn_s)[j] = __half2float(kb[base + j]);
    ((float*)v_s )[j] = vb[base + j];
  }
  for (int j = tid; j < NREL; j += 256) bias_s[j] = rel_pos_bias[h*NREL + j];

  float qr[DH];
  #pragma unroll
  for (int dd = 0; dd < DH; ++dd) qr[dd] = __half2float(qb[base + (size_t)tid*DH + dd]);
  __syncthreads();

  float l = 0.f, o[DH];
  #pragma unroll
  for (int dd = 0; dd < DH; ++dd) o[dd] = 0.f;
  const float* bptr = bias_s + (MAXT-1) + tid;  // bptr[-s] = bias[h, tid-s+299]
  for (int s = 0; s < T_; ++s) {
    float dot = 0.f;
    #pragma unroll
    for (int dd = 0; dd < DH; ++dd) dot += qr[dd]*kn_s[s][dd];
    float p = __expf(dot * 0.25f + bptr[-s]);
    l += p;
    #pragma unroll
    for (int dd = 0; dd < DH; ++dd) o[dd] += p * v_s[s][dd];
  }
  const float inv = 1.0f / l;
  #pragma unroll
  for (int dd = 0; dd < DH; ++dd)
    xattn[((size_t)bv*T_ + tid)*D_ + h*DH + dd] = o[dd]*inv;
}

// ---------------- K3: attn @ proj_w + proj_b + residual (in-place xf2) ------
__global__ __launch_bounds__(256) void k3_proj(
    const float* __restrict__ x, const short* __restrict__ pwt,
    const float* __restrict__ proj_b, float* __restrict__ xf2)
{
  __shared__ short a_s[16][136];
  const int tid = threadIdx.x;
  const int bv  = blockIdx.x / (T_/16);
  const int t0  = (blockIdx.x % (T_/16)) * 16;
  const int b   = bv / V_, v = bv % V_;

  {
    const int tok = tid >> 4, j = tid & 15;
    const float* ap = xf2 + ((size_t)bv*T_ + t0+tok)*D_ + j*8;
    float4 a0 = *(const float4*)ap;
    float4 a1 = *(const float4*)(ap+4);
    float e[8] = {a0.x,a0.y,a0.z,a0.w,a1.x,a1.y,a1.z,a1.w};
    short8 o;
    #pragma unroll
    for (int q = 0; q < 8; ++q) o[q] = f2bf(e[q]);
    *(short8*)&a_s[tok][j*8] = o;
  }
  __syncthreads();

  const int wave = tid >> 6, lane = tid & 63;
  const int col = lane & 15, quad = lane >> 4;
  short8 af[4];
  #pragma unroll
  for (int kk = 0; kk < 4; ++kk) af[kk] = *(const short8*)&a_s[col][kk*32 + quad*8];

  for (int it = 0; it < 2; ++it) {
    const int tile = wave*2 + it, n0 = tile*16;
    f32x4 acc = {0.f,0.f,0.f,0.f};
    #pragma unroll
    for (int kk = 0; kk < 4; ++kk) {
      short8 bf = *(const short8*)(pwt + (size_t)(n0+col)*128 + kk*32 + quad*8);
      acc = __builtin_amdgcn_mfma_f32_16x16x32_bf16(af[kk], bf, acc, 0, 0, 0);
    }
    const float pbv = proj_b[n0+col];
    #pragma unroll
    for (int r = 0; r < 4; ++r) {
      const int t = t0 + quad*4 + r;
      float res = x[(((size_t)b*T_ + t)*V_ + v)*D_ + n0 + col];
      xf2[((size_t)bv*T_ + t)*D_ + n0 + col] = acc[r] + pbv + res;
    }
  }
}

// ---------------- K4: LN2 + FFN (MFMA both GEMMs) + residual -> d_out -------
__global__ __launch_bounds__(256) void k4_ffn(
    const float* __restrict__ xf2, const float* __restrict__ g2, const float* __restrict__ b2,
    const short* __restrict__ w1t, const float* __restrict__ fb1,
    const short* __restrict__ w2t, const float* __restrict__ fb2,
    float* __restrict__ out)
{
  __shared__ short y_s[16][136];
  __shared__ short h_s[16][520];
  __shared__ float xf_s[16][132];
  const int tid = threadIdx.x;
  const int bv  = blockIdx.x / (T_/16);
  const int t0  = (blockIdx.x % (T_/16)) * 16;
  const int b   = bv / V_, v = bv % V_;

  { // LN2; also stash xf fp32 for the residual
    const int tok = tid >> 4, j = tid & 15;
    const float* xp = xf2 + ((size_t)bv*T_ + t0+tok)*D_ + j*8;
    float4 a0 = *(const float4*)xp;
    float4 a1 = *(const float4*)(xp+4);
    *(float4*)&xf_s[tok][j*8]     = a0;
    *(float4*)&xf_s[tok][j*8 + 4] = a1;
    float e[8] = {a0.x,a0.y,a0.z,a0.w,a1.x,a1.y,a1.z,a1.w};
    float s = 0.f;
    #pragma unroll
    for (int q = 0; q < 8; ++q) s += e[q];
    #pragma unroll
    for (int m = 1; m < 16; m <<= 1) s += __shfl_xor(s, m, 16);
    float mean = s * (1.0f/128.0f);
    float s2 = 0.f;
    #pragma unroll
    for (int q = 0; q < 8; ++q) { float d = e[q]-mean; s2 += d*d; }
    #pragma unroll
    for (int m = 1; m < 16; m <<= 1) s2 += __shfl_xor(s2, m, 16);
    float rstd = rsqrtf(s2*(1.0f/128.0f) + 1e-5f);
    float4 gA = *(const float4*)(g2 + j*8), gB = *(const float4*)(g2 + j*8 + 4);
    float4 bA = *(const float4*)(b2 + j*8), bB = *(const float4*)(b2 + j*8 + 4);
    float gg[8] = {gA.x,gA.y,gA.z,gA.w,gB.x,gB.y,gB.z,gB.w};
    float bb[8] = {bA.x,bA.y,bA.z,bA.w,bB.x,bB.y,bB.z,bB.w};
    short8 o;
    #pragma unroll
    for (int q = 0; q < 8; ++q) o[q] = f2bf((e[q]-mean)*rstd*gg[q] + bb[q]);
    *(short8*)&y_s[tok][j*8] = o;
  }
  __syncthreads();

  const int wave = tid >> 6, lane = tid & 63;
  const int col = lane & 15, quad = lane >> 4;

  { // GEMM1: [16 tok] x [512] = 32 tiles, 8 per wave; K=128
    short8 af[4];
    #pragma unroll
    for (int kk = 0; kk < 4; ++kk) af[kk] = *(const short8*)&y_s[col][kk*32 + quad*8];
    for (int it = 0; it < 8; ++it) {
      const int n0 = (wave*8 + it)*16;
      f32x4 acc = {0.f,0.f,0.f,0.f};
      #pragma unroll
      for (int kk = 0; kk < 4; ++kk) {
        short8 bf = *(const short8*)(w1t + (size_t)(n0+col)*128 + kk*32 + quad*8);
        acc = __builtin_amdgcn_mfma_f32_16x16x32_bf16(af[kk], bf, acc, 0, 0, 0);
      }
      const float b1v = fb1[n0+col];
      #pragma unroll
      for (int r = 0; r < 4; ++r) {
        float u = acc[r] + b1v;
        float g = 0.5f*u*(1.0f + erff(u*0.70710678118654752f));
        h_s[quad*4 + r][n0 + col] = f2bf(g);
      }
    }
  }
  __syncthreads();

  { // GEMM2: [16 tok] x [128] = 8 tiles, 2 per wave; K=512
    f32x4 acc[2] = {{0.f,0.f,0.f,0.f},{0.f,0.f,0.f,0.f}};
    for (int kk = 0; kk < 16; ++kk) {
      short8 a2 = *(const short8*)&h_s[col][kk*32 + quad*8];
      #pragma unroll
      for (int it = 0; it < 2; ++it) {
        const int n0 = (wave*2 + it)*16;
        short8 bf = *(const short8*)(w2t + (size_t)(n0+col)*512 + kk*32 + quad*8);
        acc[it] = __builtin_amdgcn_mfma_f32_16x16x32_bf16(a2, bf, acc[it], 0, 0, 0);
      }
    }
    #pragma unroll
    for (int it = 0; it < 2; ++it) {
      const int n0 = (wave*2 + it)*16;
      const float bo = fb2[n0+col];
      #pragma unroll
      for (int r = 0; r < 4; ++r) {
        const int row = quad*4 + r;
        float o = acc[it][r] + bo + xf_s[row][n0 + col];
        out[(((size_t)b*T_ + t0+row)*V_ + v)*D_ + n0 + col] = o;
      }
    }
  }
}

extern "C" void kernel_launch(void* const* d_in, const int* in_sizes, int n_in,
                              void* d_out, int out_size, void* d_ws, size_t ws_size,
                              hipStream_t stream)
{
  (void)in_sizes; (void)n_in; (void)out_size; (void)ws_size;
  const float* x     = (const float*)d_in[0];
  const float* g1    = (const float*)d_in[1];
  const float* b1    = (const float*)d_in[2];
  const float* qkv_w = (const float*)d_in[3];
  const float* qkv_b = (const float*)d_in[4];
  const float* pw    = (const float*)d_in[5];
  const float* pb    = (const float*)d_in[6];
  const float* ls    = (const float*)d_in[7];
  const float* rpb   = (const float*)d_in[8];
  const float* g2    = (const float*)d_in[9];
  const float* b2    = (const float*)d_in[10];
  const float* w1    = (const float*)d_in[11];
  const float* fb1   = (const float*)d_in[12];
  const float* w2    = (const float*)d_in[13];
  const float* fb2   = (const float*)d_in[14];
  float* out = (float*)d_out;

  const size_t n = (size_t)BV_*T_*D_;          // 13,107,200
  char* ws = (char*)d_ws;
  __half* qb  = (__half*)ws;                   // n fp16 = 26.2 MB
  __half* kb  = (__half*)(ws + n*2);           // n fp16
  float*  xf2 = (float*)(ws + n*4);            // n fp32 (attn out, then xf2 in-place)
  short*  qkv_wt = (short*)(ws + n*8);         // 384*128
  short*  pwt    = qkv_wt + 384*128;           // 128*128
  short*  w1t    = pwt + 128*128;              // 512*128
  short*  w2t    = w1t + 512*128;              // 128*512
  float*  vb = out;                            // v aliased onto d_out

  k0_prep  <<<256,          dim3(256), 0, stream>>>(qkv_w, pw, w1, w2, qkv_wt, pwt, w1t, w2t);
  k1_ln_qkv<<<BV_*(T_/16),  dim3(256), 0, stream>>>(x, g1, b1, qkv_wt, qkv_b, ls, qb, kb, vb);
  k2_attn  <<<BV_*H_,       dim3(256), 0, stream>>>(rpb, qb, kb, vb, xf2);
  k3_proj  <<<BV_*(T_/16),  dim3(256), 0, stream>>>(x, pwt, pb, xf2);
  k4_ffn   <<<BV_*(T_/16),  dim3(256), 0, stream>>>(xf2, g2, b2, w1t, fb1, w2t, fb2, out);
}

// Round 3
// 483.716 us; speedup vs baseline: 2.4178x; 1.3484x over previous
//
#include <hip/hip_runtime.h>
#include <hip/hip_fp16.h>
#include <math.h>

#define B_   16
#define T_   256
#define V_   25
#define D_   128
#define H_   8
#define DH   16
#define BV_  (B_*V_)        // 400
#define MAXT 300
#define NREL (2*MAXT-1)     // 599

typedef __attribute__((ext_vector_type(8))) short short8;
typedef __attribute__((ext_vector_type(4))) float f32x4;
typedef __attribute__((ext_vector_type(4))) _Float16 half4;

__device__ inline short f2bf(float f) {
  union { float f; unsigned u; } a; a.f = f;
  unsigned r = (a.u + 0x7FFF + ((a.u >> 16) & 1)) >> 16;   // RNE
  return (short)r;
}

// ---------------- K0: weight prep (fp32 -> bf16, transposed to [N][K]) ------
__global__ __launch_bounds__(256) void k0_prep(
    const float* __restrict__ qkv_w, const float* __restrict__ pw,
    const float* __restrict__ w1,    const float* __restrict__ w2,
    short* __restrict__ qkv_wt, short* __restrict__ pwt,
    short* __restrict__ w1t,    short* __restrict__ w2t)
{
  int i = blockIdx.x*256 + threadIdx.x;
  if (i < 384*128) { int n = i >> 7, k = i & 127; qkv_wt[i] = f2bf(qkv_w[k*384 + n]); }
  if (i < 128*128) { int n = i >> 7, k = i & 127; pwt[i]    = f2bf(pw[k*128 + n]); }
  if (i < 512*128) { int n = i >> 7, k = i & 127; w1t[i]    = f2bf(w1[k*512 + n]); }
  if (i < 128*512) { int n = i >> 9, k = i & 511; w2t[i]    = f2bf(w2[k*128 + n]); }
}

// ---------------- K1: LN1 + QKV (MFMA) + q/k head-norm ----------------------
// grid: BV*(T/16), 256 thr (4 waves).
// qb,kb fp16 [bh][T][16] (q pre-scaled by scale*0.25); vt fp16 [bh][s_tile][d][s_local].
__global__ __launch_bounds__(256) void k1_ln_qkv(
    const float* __restrict__ x, const float* __restrict__ g1, const float* __restrict__ b1,
    const short* __restrict__ qkv_wt, const float* __restrict__ qkv_b,
    const float* __restrict__ logit_scale,
    _Float16* __restrict__ qb, _Float16* __restrict__ kb, _Float16* __restrict__ vt)
{
  __shared__ short xn[16][136];
  const int tid = threadIdx.x;
  const int bv  = blockIdx.x / (T_/16);
  const int t0  = (blockIdx.x % (T_/16)) * 16;
  const int b   = bv / V_, v = bv % V_;

  { // LN: 16 threads per token, 8 elems each
    const int tok = tid >> 4, j = tid & 15;
    const float* xp = x + (((size_t)b*T_ + (t0+tok))*V_ + v)*D_ + j*8;
    float4 a0 = *(const float4*)xp;
    float4 a1 = *(const float4*)(xp+4);
    float e[8] = {a0.x,a0.y,a0.z,a0.w,a1.x,a1.y,a1.z,a1.w};
    float s = 0.f;
    #pragma unroll
    for (int q = 0; q < 8; ++q) s += e[q];
    #pragma unroll
    for (int m = 1; m < 16; m <<= 1) s += __shfl_xor(s, m, 16);
    float mean = s * (1.0f/128.0f);
    float s2 = 0.f;
    #pragma unroll
    for (int q = 0; q < 8; ++q) { float d = e[q]-mean; s2 += d*d; }
    #pragma unroll
    for (int m = 1; m < 16; m <<= 1) s2 += __shfl_xor(s2, m, 16);
    float rstd = rsqrtf(s2*(1.0f/128.0f) + 1e-5f);
    float4 gA = *(const float4*)(g1 + j*8), gB = *(const float4*)(g1 + j*8 + 4);
    float4 bA = *(const float4*)(b1 + j*8), bB = *(const float4*)(b1 + j*8 + 4);
    float gg[8] = {gA.x,gA.y,gA.z,gA.w,gB.x,gB.y,gB.z,gB.w};
    float bb[8] = {bA.x,bA.y,bA.z,bA.w,bB.x,bB.y,bB.z,bB.w};
    short8 o;
    #pragma unroll
    for (int q = 0; q < 8; ++q) o[q] = f2bf((e[q]-mean)*rstd*gg[q] + bb[q]);
    *(short8*)&xn[tok][j*8] = o;
  }
  __syncthreads();

  const int wave = tid >> 6, lane = tid & 63;
  const int col = lane & 15, quad = lane >> 4;
  short8 af[4];
  #pragma unroll
  for (int kk = 0; kk < 4; ++kk) af[kk] = *(const short8*)&xn[col][kk*32 + quad*8];

  for (int it = 0; it < 6; ++it) {
    const int tile = wave*6 + it;           // 0..23: 0-7 q, 8-15 k, 16-23 v
    const int n0 = tile*16;
    f32x4 acc = {0.f,0.f,0.f,0.f};
    #pragma unroll
    for (int kk = 0; kk < 4; ++kk) {
      short8 bf = *(const short8*)(qkv_wt + (size_t)(n0+col)*128 + kk*32 + quad*8);
      acc = __builtin_amdgcn_mfma_f32_16x16x32_bf16(af[kk], bf, acc, 0, 0, 0);
    }
    const float bias = qkv_b[n0+col];
    float val[4];
    #pragma unroll
    for (int r = 0; r < 4; ++r) val[r] = acc[r] + bias;
    const int h = tile & 7;
    const size_t bh = (size_t)bv*H_ + h;
    if (tile < 16) {
      float inv[4];
      #pragma unroll
      for (int r = 0; r < 4; ++r) {
        float s = val[r]*val[r];
        #pragma unroll
        for (int m = 1; m < 16; m <<= 1) s += __shfl_xor(s, m, 16);
        inv[r] = 1.0f / fmaxf(sqrtf(s), 1e-12f);
      }
      const size_t obase = (bh*T_ + (t0 + quad*4))*DH + col;
      if (tile < 8) {
        // fold the 1/sqrt(d)=0.25 score scale into q
        const float scale = __expf(fminf(logit_scale[h], 4.605170185988091f)) * 0.25f;
        #pragma unroll
        for (int r = 0; r < 4; ++r) qb[obase + (size_t)r*DH] = (_Float16)(val[r]*inv[r]*scale);
      } else {
        #pragma unroll
        for (int r = 0; r < 4; ++r) kb[obase + (size_t)r*DH] = (_Float16)(val[r]*inv[r]);
      }
    } else {
      // vt[bh][t>>4][d=col][t&15]; lane's 4 values (r=0..3) are contiguous
      half4 vh;
      #pragma unroll
      for (int r = 0; r < 4; ++r) vh[r] = (_Float16)val[r];
      *(half4*)(vt + bh*4096 + (size_t)t0*16 + col*16 + quad*4) = vh;
    }
  }
}

// ---------------- K2: attention via MFMA (S^T trick, no P transpose) --------
// grid: BV*H blocks, 256 thr (4 waves). Wave w owns query rows 64w..64w+63.
__global__ __launch_bounds__(256) void k2_attn(
    const float* __restrict__ rel_pos_bias,
    const _Float16* __restrict__ qb, const _Float16* __restrict__ kb,
    const _Float16* __restrict__ vt, float* __restrict__ xattn)
{
  __shared__ float bias_s[NREL + 1];
  const int tid = threadIdx.x;
  const int bh  = blockIdx.x;          // bv*H + h
  const int h   = bh & (H_-1);
  const int bv  = bh >> 3;
  for (int j = tid; j < NREL; j += 256) bias_s[j] = rel_pos_bias[h*NREL + j];
  __syncthreads();

  const int wave = tid >> 6, lane = tid & 63;
  const int nn = lane & 15, quad = lane >> 4;
  const size_t qkbase = (size_t)bh * (T_*DH);
  const size_t vbase  = (size_t)bh * 4096;

  // Q B-frags for this wave's 4 t-tiles: B[k=d][n=t], lane n holds Q[t][quad*4..+3]
  half4 qf[4];
  #pragma unroll
  for (int tt = 0; tt < 4; ++tt)
    qf[tt] = *(const half4*)(qb + qkbase + (size_t)(wave*64 + tt*16 + nn)*DH + quad*4);

  f32x4 o[4];
  #pragma unroll
  for (int tt = 0; tt < 4; ++tt) o[tt] = (f32x4){0.f,0.f,0.f,0.f};
  float lsum[4] = {0.f,0.f,0.f,0.f};

  // software-pipelined K/V fragment loads
  half4 kf = *(const half4*)(kb + qkbase + (size_t)nn*DH + quad*4);
  half4 vf = *(const half4*)(vt + vbase + (size_t)nn*16 + quad*4);

  for (int s16 = 0; s16 < 16; ++s16) {
    half4 kf_n, vf_n;
    if (s16 < 15) {
      kf_n = *(const half4*)(kb + qkbase + (size_t)((s16+1)*16 + nn)*DH + quad*4);
      vf_n = *(const half4*)(vt + vbase + (size_t)(s16+1)*256 + nn*16 + quad*4);
    }
    #pragma unroll
    for (int tt = 0; tt < 4; ++tt) {
      // S^T tile: A=K (m=s), B=Q (n=t) -> c[r] = S[t = 16tt+64w+nn][s = 16*s16+quad*4+r]
      f32x4 c = {0.f,0.f,0.f,0.f};
      c = __builtin_amdgcn_mfma_f32_16x16x16f16(kf, qf[tt], c, 0, 0, 0);
      const int ib = (wave*64 + tt*16 + nn) - (s16*16 + quad*4) + (MAXT-1);
      half4 pa;
      #pragma unroll
      for (int r = 0; r < 4; ++r) {
        float p = __expf(c[r] + bias_s[ib - r]);
        lsum[tt] += p;
        pa[r] = (_Float16)p;
      }
      // C-frag of S^T is exactly the A-frag of P for P@V: A[m=t][k=s]
      o[tt] = __builtin_amdgcn_mfma_f32_16x16x16f16(pa, vf, o[tt], 0, 0, 0);
    }
    kf = kf_n; vf = vf_n;
  }

  #pragma unroll
  for (int tt = 0; tt < 4; ++tt) {
    float l = lsum[tt];
    l += __shfl_xor(l, 16);
    l += __shfl_xor(l, 32);          // every lane: full sum for t = 16tt+64w+nn
    float rinv = 1.0f / l;
    #pragma unroll
    for (int r = 0; r < 4; ++r) {
      float inv = __shfl(rinv, quad*4 + r, 16);  // fetch l for t-row quad*4+r
      const int t = wave*64 + tt*16 + quad*4 + r;
      xattn[((size_t)bv*T_ + t)*D_ + h*DH + nn] = o[tt][r] * inv;
    }
  }
}

// ---------------- K3: attn @ proj_w + proj_b + residual (in-place xf2) ------
__global__ __launch_bounds__(256) void k3_proj(
    const float* __restrict__ x, const short* __restrict__ pwt,
    const float* __restrict__ proj_b, float* __restrict__ xf2)
{
  __shared__ short a_s[16][136];
  const int tid = threadIdx.x;
  const int bv  = blockIdx.x / (T_/16);
  const int t0  = (blockIdx.x % (T_/16)) * 16;
  const int b   = bv / V_, v = bv % V_;

  {
    const int tok = tid >> 4, j = tid & 15;
    const float* ap = xf2 + ((size_t)bv*T_ + t0+tok)*D_ + j*8;
    float4 a0 = *(const float4*)ap;
    float4 a1 = *(const float4*)(ap+4);
    float e[8] = {a0.x,a0.y,a0.z,a0.w,a1.x,a1.y,a1.z,a1.w};
    short8 o;
    #pragma unroll
    for (int q = 0; q < 8; ++q) o[q] = f2bf(e[q]);
    *(short8*)&a_s[tok][j*8] = o;
  }
  __syncthreads();

  const int wave = tid >> 6, lane = tid & 63;
  const int col = lane & 15, quad = lane >> 4;
  short8 af[4];
  #pragma unroll
  for (int kk = 0; kk < 4; ++kk) af[kk] = *(const short8*)&a_s[col][kk*32 + quad*8];

  for (int it = 0; it < 2; ++it) {
    const int tile = wave*2 + it, n0 = tile*16;
    f32x4 acc = {0.f,0.f,0.f,0.f};
    #pragma unroll
    for (int kk = 0; kk < 4; ++kk) {
      short8 bf = *(const short8*)(pwt + (size_t)(n0+col)*128 + kk*32 + quad*8);
      acc = __builtin_amdgcn_mfma_f32_16x16x32_bf16(af[kk], bf, acc, 0, 0, 0);
    }
    const float pbv = proj_b[n0+col];
    #pragma unroll
    for (int r = 0; r < 4; ++r) {
      const int t = t0 + quad*4 + r;
      float res = x[(((size_t)b*T_ + t)*V_ + v)*D_ + n0 + col];
      xf2[((size_t)bv*T_ + t)*D_ + n0 + col] = acc[r] + pbv + res;
    }
  }
}

// ---------------- K4: LN2 + FFN (MFMA both GEMMs) + residual -> d_out -------
__global__ __launch_bounds__(256) void k4_ffn(
    const float* __restrict__ xf2, const float* __restrict__ g2, const float* __restrict__ b2,
    const short* __restrict__ w1t, const float* __restrict__ fb1,
    const short* __restrict__ w2t, const float* __restrict__ fb2,
    float* __restrict__ out)
{
  __shared__ short y_s[16][136];
  __shared__ short h_s[16][520];
  __shared__ float xf_s[16][132];
  const int tid = threadIdx.x;
  const int bv  = blockIdx.x / (T_/16);
  const int t0  = (blockIdx.x % (T_/16)) * 16;
  const int b   = bv / V_, v = bv % V_;

  { // LN2; also stash xf fp32 for the residual
    const int tok = tid >> 4, j = tid & 15;
    const float* xp = xf2 + ((size_t)bv*T_ + t0+tok)*D_ + j*8;
    float4 a0 = *(const float4*)xp;
    float4 a1 = *(const float4*)(xp+4);
    *(float4*)&xf_s[tok][j*8]     = a0;
    *(float4*)&xf_s[tok][j*8 + 4] = a1;
    float e[8] = {a0.x,a0.y,a0.z,a0.w,a1.x,a1.y,a1.z,a1.w};
    float s = 0.f;
    #pragma unroll
    for (int q = 0; q < 8; ++q) s += e[q];
    #pragma unroll
    for (int m = 1; m < 16; m <<= 1) s += __shfl_xor(s, m, 16);
    float mean = s * (1.0f/128.0f);
    float s2 = 0.f;
    #pragma unroll
    for (int q = 0; q < 8; ++q) { float d = e[q]-mean; s2 += d*d; }
    #pragma unroll
    for (int m = 1; m < 16; m <<= 1) s2 += __shfl_xor(s2, m, 16);
    float rstd = rsqrtf(s2*(1.0f/128.0f) + 1e-5f);
    float4 gA = *(const float4*)(g2 + j*8), gB = *(const float4*)(g2 + j*8 + 4);
    float4 bA = *(const float4*)(b2 + j*8), bB = *(const float4*)(b2 + j*8 + 4);
    float gg[8] = {gA.x,gA.y,gA.z,gA.w,gB.x,gB.y,gB.z,gB.w};
    float bb[8] = {bA.x,bA.y,bA.z,bA.w,bB.x,bB.y,bB.z,bB.w};
    short8 o;
    #pragma unroll
    for (int q = 0; q < 8; ++q) o[q] = f2bf((e[q]-mean)*rstd*gg[q] + bb[q]);
    *(short8*)&y_s[tok][j*8] = o;
  }
  __syncthreads();

  const int wave = tid >> 6, lane = tid & 63;
  const int col = lane & 15, quad = lane >> 4;

  { // GEMM1: [16 tok] x [512] = 32 tiles, 8 per wave; K=128
    short8 af[4];
    #pragma unroll
    for (int kk = 0; kk < 4; ++kk) af[kk] = *(const short8*)&y_s[col][kk*32 + quad*8];
    for (int it = 0; it < 8; ++it) {
      const int n0 = (wave*8 + it)*16;
      f32x4 acc = {0.f,0.f,0.f,0.f};
      #pragma unroll
      for (int kk = 0; kk < 4; ++kk) {
        short8 bf = *(const short8*)(w1t + (size_t)(n0+col)*128 + kk*32 + quad*8);
        acc = __builtin_amdgcn_mfma_f32_16x16x32_bf16(af[kk], bf, acc, 0, 0, 0);
      }
      const float b1v = fb1[n0+col];
      #pragma unroll
      for (int r = 0; r < 4; ++r) {
        float u = acc[r] + b1v;
        float g = 0.5f*u*(1.0f + erff(u*0.70710678118654752f));
        h_s[quad*4 + r][n0 + col] = f2bf(g);
      }
    }
  }
  __syncthreads();

  { // GEMM2: [16 tok] x [128] = 8 tiles, 2 per wave; K=512
    f32x4 acc[2] = {{0.f,0.f,0.f,0.f},{0.f,0.f,0.f,0.f}};
    for (int kk = 0; kk < 16; ++kk) {
      short8 a2 = *(const short8*)&h_s[col][kk*32 + quad*8];
      #pragma unroll
      for (int it = 0; it < 2; ++it) {
        const int n0 = (wave*2 + it)*16;
        short8 bf = *(const short8*)(w2t + (size_t)(n0+col)*512 + kk*32 + quad*8);
        acc[it] = __builtin_amdgcn_mfma_f32_16x16x32_bf16(a2, bf, acc[it], 0, 0, 0);
      }
    }
    #pragma unroll
    for (int it = 0; it < 2; ++it) {
      const int n0 = (wave*2 + it)*16;
      const float bo = fb2[n0+col];
      #pragma unroll
      for (int r = 0; r < 4; ++r) {
        const int row = quad*4 + r;
        float o = acc[it][r] + bo + xf_s[row][n0 + col];
        out[(((size_t)b*T_ + t0+row)*V_ + v)*D_ + n0 + col] = o;
      }
    }
  }
}

extern "C" void kernel_launch(void* const* d_in, const int* in_sizes, int n_in,
                              void* d_out, int out_size, void* d_ws, size_t ws_size,
                              hipStream_t stream)
{
  (void)in_sizes; (void)n_in; (void)out_size; (void)ws_size;
  const float* x     = (const float*)d_in[0];
  const float* g1    = (const float*)d_in[1];
  const float* b1    = (const float*)d_in[2];
  const float* qkv_w = (const float*)d_in[3];
  const float* qkv_b = (const float*)d_in[4];
  const float* pw    = (const float*)d_in[5];
  const float* pb    = (const float*)d_in[6];
  const float* ls    = (const float*)d_in[7];
  const float* rpb   = (const float*)d_in[8];
  const float* g2    = (const float*)d_in[9];
  const float* b2    = (const float*)d_in[10];
  const float* w1    = (const float*)d_in[11];
  const float* fb1   = (const float*)d_in[12];
  const float* w2    = (const float*)d_in[13];
  const float* fb2   = (const float*)d_in[14];
  float* out = (float*)d_out;

  const size_t n = (size_t)BV_*T_*D_;          // 13,107,200
  char* ws = (char*)d_ws;
  _Float16* qb  = (_Float16*)ws;               // n fp16
  _Float16* kb  = (_Float16*)(ws + n*2);       // n fp16
  float*    xf2 = (float*)(ws + n*4);          // n fp32 (attn out, then xf2 in-place)
  _Float16* vt  = (_Float16*)(ws + n*8);       // n fp16, PV-B-frag layout
  short*  qkv_wt = (short*)(ws + n*10);        // 384*128
  short*  pwt    = qkv_wt + 384*128;           // 128*128
  short*  w1t    = pwt + 128*128;              // 512*128
  short*  w2t    = w1t + 512*128;              // 128*512

  k0_prep  <<<256,          dim3(256), 0, stream>>>(qkv_w, pw, w1, w2, qkv_wt, pwt, w1t, w2t);
  k1_ln_qkv<<<BV_*(T_/16),  dim3(256), 0, stream>>>(x, g1, b1, qkv_wt, qkv_b, ls, qb, kb, vt);
  k2_attn  <<<BV_*H_,       dim3(256), 0, stream>>>(rpb, qb, kb, vt, xf2);
  k3_proj  <<<BV_*(T_/16),  dim3(256), 0, stream>>>(x, pwt, pb, xf2);
  k4_ffn   <<<BV_*(T_/16),  dim3(256), 0, stream>>>(xf2, g2, b2, w1t, fb1, w2t, fb2, out);
}

// Round 4
// 443.659 us; speedup vs baseline: 2.6361x; 1.0903x over previous
//
#include <hip/hip_runtime.h>
#include <hip/hip_fp16.h>
#include <math.h>

#define B_   16
#define T_   256
#define V_   25
#define D_   128
#define H_   8
#define DH   16
#define BV_  (B_*V_)        // 400
#define MAXT 300
#define NREL (2*MAXT-1)     // 599

typedef __attribute__((ext_vector_type(8))) short short8;
typedef __attribute__((ext_vector_type(4))) float f32x4;
typedef __attribute__((ext_vector_type(4))) _Float16 half4;
typedef __attribute__((ext_vector_type(8))) _Float16 half8;

__device__ inline short f2bf(float f) {
  union { float f; unsigned u; } a; a.f = f;
  unsigned r = (a.u + 0x7FFF + ((a.u >> 16) & 1)) >> 16;   // RNE
  return (short)r;
}

// gelu(u) = u * sigmoid(1.595769*u*(1 + 0.044715*u^2)); |err| <= ~3e-4
__device__ inline float gelu_fast(float u) {
  float s = u * fmaf(0.0713548162726f, u*u, 1.5957691216057f);
  return u / (1.0f + __expf(-s));
}

// ---------------- K0: weight prep ------------------------------------------
// qkv_wt, pwt: bf16 [N][K]; w1t, w2t: f16 [N][K].
__global__ __launch_bounds__(256) void k0_prep(
    const float* __restrict__ qkv_w, const float* __restrict__ pw,
    const float* __restrict__ w1,    const float* __restrict__ w2,
    short* __restrict__ qkv_wt, short* __restrict__ pwt,
    _Float16* __restrict__ w1t, _Float16* __restrict__ w2t)
{
  int i = blockIdx.x*256 + threadIdx.x;
  if (i < 384*128) { int n = i >> 7, k = i & 127; qkv_wt[i] = f2bf(qkv_w[k*384 + n]); }
  if (i < 128*128) { int n = i >> 7, k = i & 127; pwt[i]    = f2bf(pw[k*128 + n]); }
  if (i < 512*128) { int n = i >> 7, k = i & 127; w1t[i]    = (_Float16)w1[k*512 + n]; }
  if (i < 128*512) { int n = i >> 9, k = i & 511; w2t[i]    = (_Float16)w2[k*128 + n]; }
}

// ---------------- K1: LN1 + QKV (MFMA, 32 tok/block) + q/k head-norm --------
// grid: BV*(T/32), 256 thr. qb,kb fp16 [bh][T][16] (q pre-scaled by scale/4);
// vt fp16 [bh][s>>4][d][s&15].
__global__ __launch_bounds__(256) void k1_ln_qkv(
    const float* __restrict__ x, const float* __restrict__ g1, const float* __restrict__ b1,
    const short* __restrict__ qkv_wt, const float* __restrict__ qkv_b,
    const float* __restrict__ logit_scale,
    _Float16* __restrict__ qb, _Float16* __restrict__ kb, _Float16* __restrict__ vt)
{
  __shared__ short xn[32][136];
  const int tid = threadIdx.x;
  const int bv  = blockIdx.x / (T_/32);
  const int t0  = (blockIdx.x % (T_/32)) * 32;
  const int b   = bv / V_, v = bv % V_;

  { // LN: 16 threads/token, 2 reps of 16 tokens
    const int j = tid & 15;
    float4 gA = *(const float4*)(g1 + j*8), gB = *(const float4*)(g1 + j*8 + 4);
    float4 bA = *(const float4*)(b1 + j*8), bB = *(const float4*)(b1 + j*8 + 4);
    float gg[8] = {gA.x,gA.y,gA.z,gA.w,gB.x,gB.y,gB.z,gB.w};
    float bb[8] = {bA.x,bA.y,bA.z,bA.w,bB.x,bB.y,bB.z,bB.w};
    for (int rep = 0; rep < 2; ++rep) {
      const int tok = rep*16 + (tid >> 4);
      const float* xp = x + (((size_t)b*T_ + (t0+tok))*V_ + v)*D_ + j*8;
      float4 a0 = *(const float4*)xp;
      float4 a1 = *(const float4*)(xp+4);
      float e[8] = {a0.x,a0.y,a0.z,a0.w,a1.x,a1.y,a1.z,a1.w};
      float s = 0.f;
      #pragma unroll
      for (int q = 0; q < 8; ++q) s += e[q];
      #pragma unroll
      for (int m = 1; m < 16; m <<= 1) s += __shfl_xor(s, m, 16);
      float mean = s * (1.0f/128.0f);
      float s2 = 0.f;
      #pragma unroll
      for (int q = 0; q < 8; ++q) { float d = e[q]-mean; s2 += d*d; }
      #pragma unroll
      for (int m = 1; m < 16; m <<= 1) s2 += __shfl_xor(s2, m, 16);
      float rstd = rsqrtf(s2*(1.0f/128.0f) + 1e-5f);
      short8 o;
      #pragma unroll
      for (int q = 0; q < 8; ++q) o[q] = f2bf((e[q]-mean)*rstd*gg[q] + bb[q]);
      *(short8*)&xn[tok][j*8] = o;
    }
  }
  __syncthreads();

  const int wave = tid >> 6, lane = tid & 63;
  const int col = lane & 15, quad = lane >> 4;
  short8 af[2][4];
  #pragma unroll
  for (int tt = 0; tt < 2; ++tt)
    #pragma unroll
    for (int kk = 0; kk < 4; ++kk)
      af[tt][kk] = *(const short8*)&xn[tt*16+col][kk*32 + quad*8];

  for (int it = 0; it < 6; ++it) {
    const int tile = wave*6 + it;           // 0..23: 0-7 q, 8-15 k, 16-23 v
    const int n0 = tile*16;
    short8 bf[4];
    #pragma unroll
    for (int kk = 0; kk < 4; ++kk)
      bf[kk] = *(const short8*)(qkv_wt + (size_t)(n0+col)*128 + kk*32 + quad*8);
    f32x4 acc[2] = {{0.f,0.f,0.f,0.f},{0.f,0.f,0.f,0.f}};
    #pragma unroll
    for (int kk = 0; kk < 4; ++kk) {
      acc[0] = __builtin_amdgcn_mfma_f32_16x16x32_bf16(af[0][kk], bf[kk], acc[0], 0, 0, 0);
      acc[1] = __builtin_amdgcn_mfma_f32_16x16x32_bf16(af[1][kk], bf[kk], acc[1], 0, 0, 0);
    }
    const float bias = qkv_b[n0+col];
    const int h = tile & 7;
    const size_t bh = (size_t)bv*H_ + h;
    if (tile < 16) {
      const float scale = (tile < 8)
        ? __expf(fminf(logit_scale[h], 4.605170185988091f)) * 0.25f : 1.0f;
      #pragma unroll
      for (int tt = 0; tt < 2; ++tt) {
        float val[4], inv[4];
        #pragma unroll
        for (int r = 0; r < 4; ++r) {
          val[r] = acc[tt][r] + bias;
          float s = val[r]*val[r];
          #pragma unroll
          for (int m = 1; m < 16; m <<= 1) s += __shfl_xor(s, m, 16);
          inv[r] = 1.0f / fmaxf(sqrtf(s), 1e-12f);
        }
        const size_t obase = (bh*T_ + (t0 + tt*16 + quad*4))*DH + col;
        if (tile < 8) {
          #pragma unroll
          for (int r = 0; r < 4; ++r) qb[obase + (size_t)r*DH] = (_Float16)(val[r]*inv[r]*scale);
        } else {
          #pragma unroll
          for (int r = 0; r < 4; ++r) kb[obase + (size_t)r*DH] = (_Float16)(val[r]*inv[r]);
        }
      }
    } else {
      #pragma unroll
      for (int tt = 0; tt < 2; ++tt) {
        half4 vh;
        #pragma unroll
        for (int r = 0; r < 4; ++r) vh[r] = (_Float16)(acc[tt][r] + bias);
        *(half4*)(vt + bh*4096 + (size_t)(t0/16 + tt)*256 + col*16 + quad*4) = vh;
      }
    }
  }
}

// ---------------- K2: attention via MFMA (S^T trick) ------------------------
__global__ __launch_bounds__(256) void k2_attn(
    const float* __restrict__ rel_pos_bias,
    const _Float16* __restrict__ qb, const _Float16* __restrict__ kb,
    const _Float16* __restrict__ vt, float* __restrict__ xattn)
{
  __shared__ float bias_s[NREL + 1];
  const int tid = threadIdx.x;
  const int bh  = blockIdx.x;          // bv*H + h
  const int h   = bh & (H_-1);
  const int bv  = bh >> 3;
  for (int j = tid; j < NREL; j += 256) bias_s[j] = rel_pos_bias[h*NREL + j];
  __syncthreads();

  const int wave = tid >> 6, lane = tid & 63;
  const int nn = lane & 15, quad = lane >> 4;
  const size_t qkbase = (size_t)bh * (T_*DH);
  const size_t vbase  = (size_t)bh * 4096;

  half4 qf[4];
  #pragma unroll
  for (int tt = 0; tt < 4; ++tt)
    qf[tt] = *(const half4*)(qb + qkbase + (size_t)(wave*64 + tt*16 + nn)*DH + quad*4);

  f32x4 o[4];
  #pragma unroll
  for (int tt = 0; tt < 4; ++tt) o[tt] = (f32x4){0.f,0.f,0.f,0.f};
  float lsum[4] = {0.f,0.f,0.f,0.f};

  half4 kf = *(const half4*)(kb + qkbase + (size_t)nn*DH + quad*4);
  half4 vf = *(const half4*)(vt + vbase + (size_t)nn*16 + quad*4);

  for (int s16 = 0; s16 < 16; ++s16) {
    half4 kf_n, vf_n;
    if (s16 < 15) {
      kf_n = *(const half4*)(kb + qkbase + (size_t)((s16+1)*16 + nn)*DH + quad*4);
      vf_n = *(const half4*)(vt + vbase + (size_t)(s16+1)*256 + nn*16 + quad*4);
    }
    #pragma unroll
    for (int tt = 0; tt < 4; ++tt) {
      f32x4 c = {0.f,0.f,0.f,0.f};
      c = __builtin_amdgcn_mfma_f32_16x16x16f16(kf, qf[tt], c, 0, 0, 0);
      const int ib = (wave*64 + tt*16 + nn) - (s16*16 + quad*4) + (MAXT-1);
      half4 pa;
      #pragma unroll
      for (int r = 0; r < 4; ++r) {
        float p = __expf(c[r] + bias_s[ib - r]);
        lsum[tt] += p;
        pa[r] = (_Float16)p;
      }
      o[tt] = __builtin_amdgcn_mfma_f32_16x16x16f16(pa, vf, o[tt], 0, 0, 0);
    }
    kf = kf_n; vf = vf_n;
  }

  #pragma unroll
  for (int tt = 0; tt < 4; ++tt) {
    float l = lsum[tt];
    l += __shfl_xor(l, 16);
    l += __shfl_xor(l, 32);
    float rinv = 1.0f / l;
    #pragma unroll
    for (int r = 0; r < 4; ++r) {
      float inv = __shfl(rinv, quad*4 + r, 16);
      const int t = wave*64 + tt*16 + quad*4 + r;
      xattn[((size_t)bv*T_ + t)*D_ + h*DH + nn] = o[tt][r] * inv;
    }
  }
}

// ---------------- K3: attn @ proj_w + proj_b + residual (64 tok/block) ------
__global__ __launch_bounds__(256) void k3_proj(
    const float* __restrict__ x, const short* __restrict__ pwt,
    const float* __restrict__ proj_b, float* __restrict__ xf2)
{
  __shared__ short a_s[64][136];
  const int tid = threadIdx.x;
  const int bv  = blockIdx.x / (T_/64);
  const int t0  = (blockIdx.x % (T_/64)) * 64;
  const int b   = bv / V_, v = bv % V_;

  {
    const int j = tid & 15;
    for (int rep = 0; rep < 4; ++rep) {
      const int tok = rep*16 + (tid >> 4);
      const float* ap = xf2 + ((size_t)bv*T_ + t0+tok)*D_ + j*8;
      float4 a0 = *(const float4*)ap;
      float4 a1 = *(const float4*)(ap+4);
      float e[8] = {a0.x,a0.y,a0.z,a0.w,a1.x,a1.y,a1.z,a1.w};
      short8 o;
      #pragma unroll
      for (int q = 0; q < 8; ++q) o[q] = f2bf(e[q]);
      *(short8*)&a_s[tok][j*8] = o;
    }
  }
  __syncthreads();

  const int wave = tid >> 6, lane = tid & 63;
  const int col = lane & 15, quad = lane >> 4;
  short8 af[4][4];
  #pragma unroll
  for (int tt = 0; tt < 4; ++tt)
    #pragma unroll
    for (int kk = 0; kk < 4; ++kk)
      af[tt][kk] = *(const short8*)&a_s[tt*16+col][kk*32 + quad*8];

  for (int it = 0; it < 2; ++it) {
    const int n0 = (wave*2 + it)*16;
    short8 bf[4];
    #pragma unroll
    for (int kk = 0; kk < 4; ++kk)
      bf[kk] = *(const short8*)(pwt + (size_t)(n0+col)*128 + kk*32 + quad*8);
    f32x4 acc[4] = {{0.f,0.f,0.f,0.f},{0.f,0.f,0.f,0.f},{0.f,0.f,0.f,0.f},{0.f,0.f,0.f,0.f}};
    #pragma unroll
    for (int kk = 0; kk < 4; ++kk)
      #pragma unroll
      for (int tt = 0; tt < 4; ++tt)
        acc[tt] = __builtin_amdgcn_mfma_f32_16x16x32_bf16(af[tt][kk], bf[kk], acc[tt], 0, 0, 0);
    const float pbv = proj_b[n0+col];
    #pragma unroll
    for (int tt = 0; tt < 4; ++tt)
      #pragma unroll
      for (int r = 0; r < 4; ++r) {
        const int t = t0 + tt*16 + quad*4 + r;
        float res = x[(((size_t)b*T_ + t)*V_ + v)*D_ + n0 + col];
        xf2[((size_t)bv*T_ + t)*D_ + n0 + col] = acc[tt][r] + pbv + res;
      }
  }
}

// ---------------- K4: LN2 + FFN fully register-chained (128 tok/block) ------
// GEMM1 computed transposed (C = H[t in lanes][n in regs]) so its C-frag is
// the A-frag of GEMM2 over that hidden k-tile — gelu in registers, no LDS h.
__global__ __launch_bounds__(256) void k4_ffn(
    const float* __restrict__ xf2, const float* __restrict__ g2, const float* __restrict__ b2,
    const _Float16* __restrict__ w1t, const float* __restrict__ fb1,
    const _Float16* __restrict__ w2t, const float* __restrict__ fb2,
    float* __restrict__ out)
{
  __shared__ _Float16 y_s[128][136];
  const int tid = threadIdx.x;
  const int bv  = blockIdx.x / (T_/128);
  const int t0  = (blockIdx.x % (T_/128)) * 128;
  const int b   = bv / V_, v = bv % V_;

  { // LN2 for 128 tokens -> y_s (f16)
    const int j = tid & 15;
    float4 gA = *(const float4*)(g2 + j*8), gB = *(const float4*)(g2 + j*8 + 4);
    float4 bA = *(const float4*)(b2 + j*8), bB = *(const float4*)(b2 + j*8 + 4);
    float gg[8] = {gA.x,gA.y,gA.z,gA.w,gB.x,gB.y,gB.z,gB.w};
    float bb[8] = {bA.x,bA.y,bA.z,bA.w,bB.x,bB.y,bB.z,bB.w};
    for (int rep = 0; rep < 8; ++rep) {
      const int tok = rep*16 + (tid >> 4);
      const float* xp = xf2 + ((size_t)bv*T_ + t0+tok)*D_ + j*8;
      float4 a0 = *(const float4*)xp;
      float4 a1 = *(const float4*)(xp+4);
      float e[8] = {a0.x,a0.y,a0.z,a0.w,a1.x,a1.y,a1.z,a1.w};
      float s = 0.f;
      #pragma unroll
      for (int q = 0; q < 8; ++q) s += e[q];
      #pragma unroll
      for (int m = 1; m < 16; m <<= 1) s += __shfl_xor(s, m, 16);
      float mean = s * (1.0f/128.0f);
      float s2 = 0.f;
      #pragma unroll
      for (int q = 0; q < 8; ++q) { float d = e[q]-mean; s2 += d*d; }
      #pragma unroll
      for (int m = 1; m < 16; m <<= 1) s2 += __shfl_xor(s2, m, 16);
      float rstd = rsqrtf(s2*(1.0f/128.0f) + 1e-5f);
      half8 o;
      #pragma unroll
      for (int q = 0; q < 8; ++q) o[q] = (_Float16)((e[q]-mean)*rstd*gg[q] + bb[q]);
      *(half8*)&y_s[tok][j*8] = o;
    }
  }
  __syncthreads();

  const int wave = tid >> 6, lane = tid & 63;
  const int col = lane & 15, quad = lane >> 4;
  const int tw = t0 + wave*32;     // wave owns 32 tokens (2 t-tiles)

  // Y B-frags (B[k=feat][n=t]) hoisted for all 32 hidden iterations
  half8 yf[2][4];
  #pragma unroll
  for (int tt = 0; tt < 2; ++tt)
    #pragma unroll
    for (int kk = 0; kk < 4; ++kk)
      yf[tt][kk] = *(const half8*)&y_s[wave*32 + tt*16 + col][kk*32 + quad*8];

  f32x4 acc2[2][8];
  #pragma unroll
  for (int tt = 0; tt < 2; ++tt)
    #pragma unroll
    for (int ot = 0; ot < 8; ++ot) acc2[tt][ot] = (f32x4){0.f,0.f,0.f,0.f};

  for (int hn = 0; hn < 32; ++hn) {
    // GEMM1^T: A = W1 (m=hidden, k=feat), B = Y -> C[t in lanes][hidden in regs]
    half8 w1f[4];
    #pragma unroll
    for (int kk = 0; kk < 4; ++kk)
      w1f[kk] = *(const half8*)(w1t + (size_t)(hn*16+col)*128 + kk*32 + quad*8);
    f32x4 c0 = {0.f,0.f,0.f,0.f}, c1 = {0.f,0.f,0.f,0.f};
    #pragma unroll
    for (int kk = 0; kk < 4; ++kk) {
      c0 = __builtin_amdgcn_mfma_f32_16x16x32_f16(w1f[kk], yf[0][kk], c0, 0, 0, 0);
      c1 = __builtin_amdgcn_mfma_f32_16x16x32_f16(w1f[kk], yf[1][kk], c1, 0, 0, 0);
    }
    const f32x4 b1v = *(const f32x4*)(fb1 + hn*16 + quad*4);
    half4 pa0, pa1;
    #pragma unroll
    for (int r = 0; r < 4; ++r) {
      pa0[r] = (_Float16)gelu_fast(c0[r] + b1v[r]);
      pa1[r] = (_Float16)gelu_fast(c1[r] + b1v[r]);
    }
    // GEMM2: A = gelu(H) (chained), B = W2; accumulate over hidden tiles
    #pragma unroll
    for (int ot = 0; ot < 8; ++ot) {
      half4 w2f = *(const half4*)(w2t + (size_t)(ot*16+col)*512 + hn*16 + quad*4);
      acc2[0][ot] = __builtin_amdgcn_mfma_f32_16x16x16f16(pa0, w2f, acc2[0][ot], 0, 0, 0);
      acc2[1][ot] = __builtin_amdgcn_mfma_f32_16x16x16f16(pa1, w2f, acc2[1][ot], 0, 0, 0);
    }
  }

  // epilogue: + fb2 + residual (re-read xf2), store to permuted out
  #pragma unroll
  for (int tt = 0; tt < 2; ++tt)
    #pragma unroll
    for (int ot = 0; ot < 8; ++ot) {
      const float bo = fb2[ot*16 + col];
      #pragma unroll
      for (int r = 0; r < 4; ++r) {
        const int t = tw + tt*16 + quad*4 + r;
        float val = acc2[tt][ot][r] + bo + xf2[((size_t)bv*T_ + t)*D_ + ot*16 + col];
        out[(((size_t)b*T_ + t)*V_ + v)*D_ + ot*16 + col] = val;
      }
    }
}

extern "C" void kernel_launch(void* const* d_in, const int* in_sizes, int n_in,
                              void* d_out, int out_size, void* d_ws, size_t ws_size,
                              hipStream_t stream)
{
  (void)in_sizes; (void)n_in; (void)out_size; (void)ws_size;
  const float* x     = (const float*)d_in[0];
  const float* g1    = (const float*)d_in[1];
  const float* b1    = (const float*)d_in[2];
  const float* qkv_w = (const float*)d_in[3];
  const float* qkv_b = (const float*)d_in[4];
  const float* pw    = (const float*)d_in[5];
  const float* pb    = (const float*)d_in[6];
  const float* ls    = (const float*)d_in[7];
  const float* rpb   = (const float*)d_in[8];
  const float* g2    = (const float*)d_in[9];
  const float* b2    = (const float*)d_in[10];
  const float* w1    = (const float*)d_in[11];
  const float* fb1   = (const float*)d_in[12];
  const float* w2    = (const float*)d_in[13];
  const float* fb2   = (const float*)d_in[14];
  float* out = (float*)d_out;

  const size_t n = (size_t)BV_*T_*D_;          // 13,107,200
  char* ws = (char*)d_ws;
  _Float16* qb  = (_Float16*)ws;               // n fp16
  _Float16* kb  = (_Float16*)(ws + n*2);       // n fp16
  float*    xf2 = (float*)(ws + n*4);          // n fp32 (attn out, then xf2 in-place)
  _Float16* vt  = (_Float16*)(ws + n*8);       // n fp16, PV-B-frag layout
  short*    qkv_wt = (short*)(ws + n*10);      // 384*128 bf16
  short*    pwt    = qkv_wt + 384*128;         // 128*128 bf16
  _Float16* w1t    = (_Float16*)(pwt + 128*128);   // 512*128 f16
  _Float16* w2t    = w1t + 512*128;                // 128*512 f16

  k0_prep  <<<256,          dim3(256), 0, stream>>>(qkv_w, pw, w1, w2, qkv_wt, pwt, w1t, w2t);
  k1_ln_qkv<<<BV_*(T_/32),  dim3(256), 0, stream>>>(x, g1, b1, qkv_wt, qkv_b, ls, qb, kb, vt);
  k2_attn  <<<BV_*H_,       dim3(256), 0, stream>>>(rpb, qb, kb, vt, xf2);
  k3_proj  <<<BV_*(T_/64),  dim3(256), 0, stream>>>(x, pwt, pb, xf2);
  k4_ffn   <<<BV_*(T_/128), dim3(256), 0, stream>>>(xf2, g2, b2, w1t, fb1, w2t, fb2, out);
}

// Round 5
// 345.741 us; speedup vs baseline: 3.3826x; 1.2832x over previous
//
#include <hip/hip_runtime.h>
#include <hip/hip_fp16.h>
#include <math.h>

#define B_   16
#define T_   256
#define V_   25
#define D_   128
#define H_   8
#define DH   16
#define BV_  (B_*V_)        // 400
#define MAXT 300
#define NREL (2*MAXT-1)     // 599

typedef __attribute__((ext_vector_type(8))) short short8;
typedef __attribute__((ext_vector_type(4))) float f32x4;
typedef __attribute__((ext_vector_type(4))) _Float16 half4;
typedef __attribute__((ext_vector_type(8))) _Float16 half8;

__device__ inline short f2bf(float f) {
  union { float f; unsigned u; } a; a.f = f;
  unsigned r = (a.u + 0x7FFF + ((a.u >> 16) & 1)) >> 16;   // RNE
  return (short)r;
}

// gelu(u) ~= u * sigmoid(1.595769*u*(1 + 0.044715*u^2)); |err| <= ~3e-4
__device__ inline float gelu_fast(float u) {
  float s = u * fmaf(0.0713548162726f, u*u, 1.5957691216057f);
  return u * __builtin_amdgcn_rcpf(1.0f + __expf(-s));
}

// ---------------- K0: weight prep ------------------------------------------
// qkv_wt, pwt: bf16 [N][K]; w1t: f16 [N=512][K=128];
// w2t: f16 FRAG-LINEAR [ot(8)][hn(32)][lane(64)][r(4)]:
//   element = w2[k = hn*16 + (lane>>4)*4 + r][n = ot*16 + (lane&15)]
__global__ __launch_bounds__(256) void k0_prep(
    const float* __restrict__ qkv_w, const float* __restrict__ pw,
    const float* __restrict__ w1,    const float* __restrict__ w2,
    short* __restrict__ qkv_wt, short* __restrict__ pwt,
    _Float16* __restrict__ w1t, _Float16* __restrict__ w2t)
{
  int i = blockIdx.x*256 + threadIdx.x;
  if (i < 384*128) { int n = i >> 7, k = i & 127; qkv_wt[i] = f2bf(qkv_w[k*384 + n]); }
  if (i < 128*128) { int n = i >> 7, k = i & 127; pwt[i]    = f2bf(pw[k*128 + n]); }
  if (i < 512*128) { int n = i >> 7, k = i & 127; w1t[i]    = (_Float16)w1[k*512 + n]; }
  if (i < 128*512) {
    int r = i & 3, lane = (i >> 2) & 63, hn = (i >> 8) & 31, ot = i >> 13;
    int k = hn*16 + (lane >> 4)*4 + r;
    int n = ot*16 + (lane & 15);
    w2t[i] = (_Float16)w2[k*128 + n];
  }
}

// ---------------- K1: LN1 + QKV (MFMA, 64 tok/block) + q/k head-norm --------
// grid: BV*(T/64), 256 thr. qb,kb fp16 [bh][T][16] (q pre-scaled by scale/4);
// vt fp16 [bh][s>>4][d][s&15].
__global__ __launch_bounds__(256) void k1_ln_qkv(
    const float* __restrict__ x, const float* __restrict__ g1, const float* __restrict__ b1,
    const short* __restrict__ qkv_wt, const float* __restrict__ qkv_b,
    const float* __restrict__ logit_scale,
    _Float16* __restrict__ qb, _Float16* __restrict__ kb, _Float16* __restrict__ vt)
{
  __shared__ short xn[64][136];
  const int tid = threadIdx.x;
  const int bv  = blockIdx.x / (T_/64);
  const int t0  = (blockIdx.x % (T_/64)) * 64;
  const int b   = bv / V_, v = bv % V_;

  { // LN: 16 threads/token, 4 reps of 16 tokens
    const int j = tid & 15;
    float4 gA = *(const float4*)(g1 + j*8), gB = *(const float4*)(g1 + j*8 + 4);
    float4 bA = *(const float4*)(b1 + j*8), bB = *(const float4*)(b1 + j*8 + 4);
    float gg[8] = {gA.x,gA.y,gA.z,gA.w,gB.x,gB.y,gB.z,gB.w};
    float bb[8] = {bA.x,bA.y,bA.z,bA.w,bB.x,bB.y,bB.z,bB.w};
    for (int rep = 0; rep < 4; ++rep) {
      const int tok = rep*16 + (tid >> 4);
      const float* xp = x + (((size_t)b*T_ + (t0+tok))*V_ + v)*D_ + j*8;
      float4 a0 = *(const float4*)xp;
      float4 a1 = *(const float4*)(xp+4);
      float e[8] = {a0.x,a0.y,a0.z,a0.w,a1.x,a1.y,a1.z,a1.w};
      float s = 0.f;
      #pragma unroll
      for (int q = 0; q < 8; ++q) s += e[q];
      #pragma unroll
      for (int m = 1; m < 16; m <<= 1) s += __shfl_xor(s, m, 16);
      float mean = s * (1.0f/128.0f);
      float s2 = 0.f;
      #pragma unroll
      for (int q = 0; q < 8; ++q) { float d = e[q]-mean; s2 += d*d; }
      #pragma unroll
      for (int m = 1; m < 16; m <<= 1) s2 += __shfl_xor(s2, m, 16);
      float rstd = rsqrtf(s2*(1.0f/128.0f) + 1e-5f);
      short8 o;
      #pragma unroll
      for (int q = 0; q < 8; ++q) o[q] = f2bf((e[q]-mean)*rstd*gg[q] + bb[q]);
      *(short8*)&xn[tok][j*8] = o;
    }
  }
  __syncthreads();

  const int wave = tid >> 6, lane = tid & 63;
  const int col = lane & 15, quad = lane >> 4;
  short8 af[4][4];
  #pragma unroll
  for (int tt = 0; tt < 4; ++tt)
    #pragma unroll
    for (int kk = 0; kk < 4; ++kk)
      af[tt][kk] = *(const short8*)&xn[tt*16+col][kk*32 + quad*8];

  for (int it = 0; it < 6; ++it) {
    const int tile = wave*6 + it;           // 0..23: 0-7 q, 8-15 k, 16-23 v
    const int n0 = tile*16;
    short8 bf[4];
    #pragma unroll
    for (int kk = 0; kk < 4; ++kk)
      bf[kk] = *(const short8*)(qkv_wt + (size_t)(n0+col)*128 + kk*32 + quad*8);
    f32x4 acc[4] = {{0.f,0.f,0.f,0.f},{0.f,0.f,0.f,0.f},{0.f,0.f,0.f,0.f},{0.f,0.f,0.f,0.f}};
    #pragma unroll
    for (int kk = 0; kk < 4; ++kk)
      #pragma unroll
      for (int tt = 0; tt < 4; ++tt)
        acc[tt] = __builtin_amdgcn_mfma_f32_16x16x32_bf16(af[tt][kk], bf[kk], acc[tt], 0, 0, 0);
    const float bias = qkv_b[n0+col];
    const int h = tile & 7;
    const size_t bh = (size_t)bv*H_ + h;
    if (tile < 16) {
      const float scale = (tile < 8)
        ? __expf(fminf(logit_scale[h], 4.605170185988091f)) * 0.25f : 1.0f;
      #pragma unroll
      for (int tt = 0; tt < 4; ++tt) {
        float val[4], inv[4];
        #pragma unroll
        for (int r = 0; r < 4; ++r) {
          val[r] = acc[tt][r] + bias;
          float s = val[r]*val[r];
          #pragma unroll
          for (int m = 1; m < 16; m <<= 1) s += __shfl_xor(s, m, 16);
          inv[r] = 1.0f / fmaxf(sqrtf(s), 1e-12f);
        }
        const size_t obase = (bh*T_ + (t0 + tt*16 + quad*4))*DH + col;
        if (tile < 8) {
          #pragma unroll
          for (int r = 0; r < 4; ++r) qb[obase + (size_t)r*DH] = (_Float16)(val[r]*inv[r]*scale);
        } else {
          #pragma unroll
          for (int r = 0; r < 4; ++r) kb[obase + (size_t)r*DH] = (_Float16)(val[r]*inv[r]);
        }
      }
    } else {
      #pragma unroll
      for (int tt = 0; tt < 4; ++tt) {
        half4 vh;
        #pragma unroll
        for (int r = 0; r < 4; ++r) vh[r] = (_Float16)(acc[tt][r] + bias);
        *(half4*)(vt + bh*4096 + (size_t)(t0/16 + tt)*256 + col*16 + quad*4) = vh;
      }
    }
  }
}

// ---------------- K2: attention via MFMA (S^T trick) ------------------------
__global__ __launch_bounds__(256) void k2_attn(
    const float* __restrict__ rel_pos_bias,
    const _Float16* __restrict__ qb, const _Float16* __restrict__ kb,
    const _Float16* __restrict__ vt, float* __restrict__ xattn)
{
  __shared__ float bias_s[NREL + 1];
  const int tid = threadIdx.x;
  const int bh  = blockIdx.x;          // bv*H + h
  const int h   = bh & (H_-1);
  const int bv  = bh >> 3;
  for (int j = tid; j < NREL; j += 256) bias_s[j] = rel_pos_bias[h*NREL + j];
  __syncthreads();

  const int wave = tid >> 6, lane = tid & 63;
  const int nn = lane & 15, quad = lane >> 4;
  const size_t qkbase = (size_t)bh * (T_*DH);
  const size_t vbase  = (size_t)bh * 4096;

  half4 qf[4];
  #pragma unroll
  for (int tt = 0; tt < 4; ++tt)
    qf[tt] = *(const half4*)(qb + qkbase + (size_t)(wave*64 + tt*16 + nn)*DH + quad*4);

  f32x4 o[4];
  #pragma unroll
  for (int tt = 0; tt < 4; ++tt) o[tt] = (f32x4){0.f,0.f,0.f,0.f};
  float lsum[4] = {0.f,0.f,0.f,0.f};

  half4 kf = *(const half4*)(kb + qkbase + (size_t)nn*DH + quad*4);
  half4 vf = *(const half4*)(vt + vbase + (size_t)nn*16 + quad*4);

  for (int s16 = 0; s16 < 16; ++s16) {
    half4 kf_n, vf_n;
    if (s16 < 15) {
      kf_n = *(const half4*)(kb + qkbase + (size_t)((s16+1)*16 + nn)*DH + quad*4);
      vf_n = *(const half4*)(vt + vbase + (size_t)(s16+1)*256 + nn*16 + quad*4);
    }
    #pragma unroll
    for (int tt = 0; tt < 4; ++tt) {
      f32x4 c = {0.f,0.f,0.f,0.f};
      c = __builtin_amdgcn_mfma_f32_16x16x16f16(kf, qf[tt], c, 0, 0, 0);
      const int ib = (wave*64 + tt*16 + nn) - (s16*16 + quad*4) + (MAXT-1);
      half4 pa;
      #pragma unroll
      for (int r = 0; r < 4; ++r) {
        float p = __expf(c[r] + bias_s[ib - r]);
        lsum[tt] += p;
        pa[r] = (_Float16)p;
      }
      o[tt] = __builtin_amdgcn_mfma_f32_16x16x16f16(pa, vf, o[tt], 0, 0, 0);
    }
    kf = kf_n; vf = vf_n;
  }

  #pragma unroll
  for (int tt = 0; tt < 4; ++tt) {
    float l = lsum[tt];
    l += __shfl_xor(l, 16);
    l += __shfl_xor(l, 32);
    float rinv = 1.0f / l;
    #pragma unroll
    for (int r = 0; r < 4; ++r) {
      float inv = __shfl(rinv, quad*4 + r, 16);
      const int t = wave*64 + tt*16 + quad*4 + r;
      xattn[((size_t)bv*T_ + t)*D_ + h*DH + nn] = o[tt][r] * inv;
    }
  }
}

// ---------------- K3: attn @ proj_w + proj_b + residual (64 tok/block) ------
__global__ __launch_bounds__(256) void k3_proj(
    const float* __restrict__ x, const short* __restrict__ pwt,
    const float* __restrict__ proj_b, float* __restrict__ xf2)
{
  __shared__ short a_s[64][136];
  const int tid = threadIdx.x;
  const int bv  = blockIdx.x / (T_/64);
  const int t0  = (blockIdx.x % (T_/64)) * 64;
  const int b   = bv / V_, v = bv % V_;

  {
    const int j = tid & 15;
    for (int rep = 0; rep < 4; ++rep) {
      const int tok = rep*16 + (tid >> 4);
      const float* ap = xf2 + ((size_t)bv*T_ + t0+tok)*D_ + j*8;
      float4 a0 = *(const float4*)ap;
      float4 a1 = *(const float4*)(ap+4);
      float e[8] = {a0.x,a0.y,a0.z,a0.w,a1.x,a1.y,a1.z,a1.w};
      short8 o;
      #pragma unroll
      for (int q = 0; q < 8; ++q) o[q] = f2bf(e[q]);
      *(short8*)&a_s[tok][j*8] = o;
    }
  }
  __syncthreads();

  const int wave = tid >> 6, lane = tid & 63;
  const int col = lane & 15, quad = lane >> 4;
  short8 af[4][4];
  #pragma unroll
  for (int tt = 0; tt < 4; ++tt)
    #pragma unroll
    for (int kk = 0; kk < 4; ++kk)
      af[tt][kk] = *(const short8*)&a_s[tt*16+col][kk*32 + quad*8];

  for (int it = 0; it < 2; ++it) {
    const int n0 = (wave*2 + it)*16;
    short8 bf[4];
    #pragma unroll
    for (int kk = 0; kk < 4; ++kk)
      bf[kk] = *(const short8*)(pwt + (size_t)(n0+col)*128 + kk*32 + quad*8);
    f32x4 acc[4] = {{0.f,0.f,0.f,0.f},{0.f,0.f,0.f,0.f},{0.f,0.f,0.f,0.f},{0.f,0.f,0.f,0.f}};
    #pragma unroll
    for (int kk = 0; kk < 4; ++kk)
      #pragma unroll
      for (int tt = 0; tt < 4; ++tt)
        acc[tt] = __builtin_amdgcn_mfma_f32_16x16x32_bf16(af[tt][kk], bf[kk], acc[tt], 0, 0, 0);
    const float pbv = proj_b[n0+col];
    #pragma unroll
    for (int tt = 0; tt < 4; ++tt)
      #pragma unroll
      for (int r = 0; r < 4; ++r) {
        const int t = t0 + tt*16 + quad*4 + r;
        float res = x[(((size_t)b*T_ + t)*V_ + v)*D_ + n0 + col];
        xf2[((size_t)bv*T_ + t)*D_ + n0 + col] = acc[tt][r] + pbv + res;
      }
  }
}

// ---------------- K4: LN2 + FFN register-chained, LDS-staged weights --------
// 128 tok/block, 4 waves. Hidden processed in 8 chunks of 64; per chunk the
// block cooperatively stages w1 (rows) + w2 (frag-linear) into LDS.
__global__ __launch_bounds__(256) void k4_ffn(
    const float* __restrict__ xf2, const float* __restrict__ g2, const float* __restrict__ b2,
    const _Float16* __restrict__ w1t, const float* __restrict__ fb1,
    const _Float16* __restrict__ w2t, const float* __restrict__ fb2,
    float* __restrict__ out)
{
  __shared__ _Float16 y_s[128][136];
  __shared__ _Float16 w1c[64][136];
  __shared__ _Float16 w2c[8192];     // [ot(8)][hk(4)][lane(64)][r(4)]
  const int tid = threadIdx.x;
  const int bv  = blockIdx.x / (T_/128);
  const int t0  = (blockIdx.x % (T_/128)) * 128;
  const int b   = bv / V_, v = bv % V_;

  { // LN2 for 128 tokens -> y_s (f16)
    const int j = tid & 15;
    float4 gA = *(const float4*)(g2 + j*8), gB = *(const float4*)(g2 + j*8 + 4);
    float4 bA = *(const float4*)(b2 + j*8), bB = *(const float4*)(b2 + j*8 + 4);
    float gg[8] = {gA.x,gA.y,gA.z,gA.w,gB.x,gB.y,gB.z,gB.w};
    float bb[8] = {bA.x,bA.y,bA.z,bA.w,bB.x,bB.y,bB.z,bB.w};
    for (int rep = 0; rep < 8; ++rep) {
      const int tok = rep*16 + (tid >> 4);
      const float* xp = xf2 + ((size_t)bv*T_ + t0+tok)*D_ + j*8;
      float4 a0 = *(const float4*)xp;
      float4 a1 = *(const float4*)(xp+4);
      float e[8] = {a0.x,a0.y,a0.z,a0.w,a1.x,a1.y,a1.z,a1.w};
      float s = 0.f;
      #pragma unroll
      for (int q = 0; q < 8; ++q) s += e[q];
      #pragma unroll
      for (int m = 1; m < 16; m <<= 1) s += __shfl_xor(s, m, 16);
      float mean = s * (1.0f/128.0f);
      float s2 = 0.f;
      #pragma unroll
      for (int q = 0; q < 8; ++q) { float d = e[q]-mean; s2 += d*d; }
      #pragma unroll
      for (int m = 1; m < 16; m <<= 1) s2 += __shfl_xor(s2, m, 16);
      float rstd = rsqrtf(s2*(1.0f/128.0f) + 1e-5f);
      half8 o;
      #pragma unroll
      for (int q = 0; q < 8; ++q) o[q] = (_Float16)((e[q]-mean)*rstd*gg[q] + bb[q]);
      *(half8*)&y_s[tok][j*8] = o;
    }
  }
  __syncthreads();

  const int wave = tid >> 6, lane = tid & 63;
  const int col = lane & 15, quad = lane >> 4;

  // Y B-frags hoisted for the whole hidden loop
  half8 yf[2][4];
  #pragma unroll
  for (int tt = 0; tt < 2; ++tt)
    #pragma unroll
    for (int kk = 0; kk < 4; ++kk)
      yf[tt][kk] = *(const half8*)&y_s[wave*32 + tt*16 + col][kk*32 + quad*8];

  f32x4 acc2[2][8];
  #pragma unroll
  for (int tt = 0; tt < 2; ++tt)
    #pragma unroll
    for (int ot = 0; ot < 8; ++ot) acc2[tt][ot] = (f32x4){0.f,0.f,0.f,0.f};

  for (int c = 0; c < 8; ++c) {
    __syncthreads();   // previous chunk's LDS reads complete
    // stage w1 rows [c*64, c*64+64) : 1024 units x 16B
    #pragma unroll
    for (int j = 0; j < 4; ++j) {
      const int u = j*256 + tid;
      const int row = u >> 4, seg = u & 15;
      *(half8*)&w1c[row][seg*8] = *(const half8*)(w1t + (size_t)(c*64+row)*128 + seg*8);
    }
    // stage w2 frag-linear chunk: for hn in [c*4, c*4+4): 1024 units x 16B
    #pragma unroll
    for (int j = 0; j < 4; ++j) {
      const int u = j*256 + tid;
      const int off16 = u & 31, hk = (u >> 5) & 3, ot = u >> 7;
      *(half8*)&w2c[(size_t)u*8] =
        *(const half8*)(w2t + ((size_t)(ot*32 + c*4 + hk)*64)*4 + off16*8);
    }
    __syncthreads();

    #pragma unroll
    for (int ht = 0; ht < 4; ++ht) {
      half8 w1f[4];
      #pragma unroll
      for (int kk = 0; kk < 4; ++kk)
        w1f[kk] = *(const half8*)&w1c[ht*16+col][kk*32 + quad*8];
      f32x4 c0 = {0.f,0.f,0.f,0.f}, c1 = {0.f,0.f,0.f,0.f};
      #pragma unroll
      for (int kk = 0; kk < 4; ++kk) {
        c0 = __builtin_amdgcn_mfma_f32_16x16x32_f16(w1f[kk], yf[0][kk], c0, 0, 0, 0);
        c1 = __builtin_amdgcn_mfma_f32_16x16x32_f16(w1f[kk], yf[1][kk], c1, 0, 0, 0);
      }
      const int hn = c*4 + ht;
      const f32x4 b1v = *(const f32x4*)(fb1 + hn*16 + quad*4);
      half4 pa0, pa1;
      #pragma unroll
      for (int r = 0; r < 4; ++r) {
        pa0[r] = (_Float16)gelu_fast(c0[r] + b1v[r]);
        pa1[r] = (_Float16)gelu_fast(c1[r] + b1v[r]);
      }
      #pragma unroll
      for (int ot = 0; ot < 8; ++ot) {
        half4 w2f = *(const half4*)&w2c[((ot*4 + ht)*64 + lane)*4];
        acc2[0][ot] = __builtin_amdgcn_mfma_f32_16x16x16f16(pa0, w2f, acc2[0][ot], 0, 0, 0);
        acc2[1][ot] = __builtin_amdgcn_mfma_f32_16x16x16f16(pa1, w2f, acc2[1][ot], 0, 0, 0);
      }
    }
  }

  // epilogue: + fb2 + residual (re-read xf2), store to permuted out
  const int tw = t0 + wave*32;
  #pragma unroll
  for (int tt = 0; tt < 2; ++tt)
    #pragma unroll
    for (int ot = 0; ot < 8; ++ot) {
      const float bo = fb2[ot*16 + col];
      #pragma unroll
      for (int r = 0; r < 4; ++r) {
        const int t = tw + tt*16 + quad*4 + r;
        float val = acc2[tt][ot][r] + bo + xf2[((size_t)bv*T_ + t)*D_ + ot*16 + col];
        out[(((size_t)b*T_ + t)*V_ + v)*D_ + ot*16 + col] = val;
      }
    }
}

extern "C" void kernel_launch(void* const* d_in, const int* in_sizes, int n_in,
                              void* d_out, int out_size, void* d_ws, size_t ws_size,
                              hipStream_t stream)
{
  (void)in_sizes; (void)n_in; (void)out_size; (void)ws_size;
  const float* x     = (const float*)d_in[0];
  const float* g1    = (const float*)d_in[1];
  const float* b1    = (const float*)d_in[2];
  const float* qkv_w = (const float*)d_in[3];
  const float* qkv_b = (const float*)d_in[4];
  const float* pw    = (const float*)d_in[5];
  const float* pb    = (const float*)d_in[6];
  const float* ls    = (const float*)d_in[7];
  const float* rpb   = (const float*)d_in[8];
  const float* g2    = (const float*)d_in[9];
  const float* b2    = (const float*)d_in[10];
  const float* w1    = (const float*)d_in[11];
  const float* fb1   = (const float*)d_in[12];
  const float* w2    = (const float*)d_in[13];
  const float* fb2   = (const float*)d_in[14];
  float* out = (float*)d_out;

  const size_t n = (size_t)BV_*T_*D_;          // 13,107,200
  char* ws = (char*)d_ws;
  _Float16* qb  = (_Float16*)ws;               // n fp16
  _Float16* kb  = (_Float16*)(ws + n*2);       // n fp16
  float*    xf2 = (float*)(ws + n*4);          // n fp32 (attn out, then xf2 in-place)
  _Float16* vt  = (_Float16*)(ws + n*8);       // n fp16, PV-B-frag layout
  short*    qkv_wt = (short*)(ws + n*10);      // 384*128 bf16
  short*    pwt    = qkv_wt + 384*128;         // 128*128 bf16
  _Float16* w1t    = (_Float16*)(pwt + 128*128);   // 512*128 f16
  _Float16* w2t    = w1t + 512*128;                // 128*512 f16 frag-linear

  k0_prep  <<<256,          dim3(256), 0, stream>>>(qkv_w, pw, w1, w2, qkv_wt, pwt, w1t, w2t);
  k1_ln_qkv<<<BV_*(T_/64),  dim3(256), 0, stream>>>(x, g1, b1, qkv_wt, qkv_b, ls, qb, kb, vt);
  k2_attn  <<<BV_*H_,       dim3(256), 0, stream>>>(rpb, qb, kb, vt, xf2);
  k3_proj  <<<BV_*(T_/64),  dim3(256), 0, stream>>>(x, pwt, pb, xf2);
  k4_ffn   <<<BV_*(T_/128), dim3(256), 0, stream>>>(xf2, g2, b2, w1t, fb1, w2t, fb2, out);
}